// Round 10
// baseline (1868.529 us; speedup 1.0000x reference)
//
#include <hip/hip_runtime.h>

#define TT 2048     // tokens
#define HD 2048     // hidden dim
#define FD 1408     // expert intermediate
#define NE 16       // routed experts
#define NG 18       // routed + 2 shared pseudo-experts

typedef __attribute__((ext_vector_type(4))) float f32x4;
typedef __attribute__((ext_vector_type(8))) short short8;
typedef __attribute__((ext_vector_type(8))) __bf16 bf16x8;
typedef __attribute__((ext_vector_type(4))) unsigned short u16x4;
typedef __attribute__((ext_vector_type(8))) unsigned short u16x8;
typedef __attribute__((ext_vector_type(4))) unsigned int u32x4;

__device__ __forceinline__ unsigned short f2bf(float f) {
  unsigned u = __builtin_bit_cast(unsigned, f);
  u += 0x7fffu + ((u >> 16) & 1u);   // RNE
  return (unsigned short)(u >> 16);
}
// packed 2xf32 -> 2xbf16 in one VALU instruction
__device__ __forceinline__ unsigned cvt_pk(float lo, float hi) {
  unsigned r;
  asm("v_cvt_pk_bf16_f32 %0, %1, %2" : "=v"(r) : "v"(lo), "v"(hi));
  return r;
}

template <typename T>
__device__ __forceinline__ auto mfma_try(T a, T b, f32x4 c, int)
    -> decltype(__builtin_amdgcn_mfma_f32_16x16x32_bf16(a, b, c, 0, 0, 0)) {
  return __builtin_amdgcn_mfma_f32_16x16x32_bf16(a, b, c, 0, 0, 0);
}
template <typename T, typename BV = bf16x8>
__device__ __forceinline__ f32x4 mfma_try(T a, T b, f32x4 c, long) {
  BV aa = __builtin_bit_cast(BV, a);
  BV bb = __builtin_bit_cast(BV, b);
  return __builtin_amdgcn_mfma_f32_16x16x32_bf16(aa, bb, c, 0, 0, 0);
}
__device__ __forceinline__ f32x4 mfma16(short8 a, short8 b, f32x4 c) {
  return mfma_try(a, b, c, 0);
}

// async 16B global->LDS (linear dest: wave base + lane*16)
__device__ __forceinline__ void gload16(const void* g, void* l) {
  __builtin_amdgcn_global_load_lds(
      (const __attribute__((address_space(1))) void*)g,
      (__attribute__((address_space(3))) void*)l, 16, 0, 0);
}

#define CB1 (FD / 64)               // 22 column-blocks, gemm1
#define CB2 (HD / 128)              // 16 column-blocks, gemm2
#define MAXW1 2464
#define MAXW2 1792

// ---------------- gate: logits -> softmax -> top4 -> dense weights ----------
__global__ void gate_kernel(const float* __restrict__ x, const float* __restrict__ gw,
                            float* __restrict__ dense_w) {
  int wid = threadIdx.x >> 6;
  int lane = threadIdx.x & 63;
  int t = blockIdx.x * 4 + wid;
  if (t >= TT) return;
  const float* xr = x + (size_t)t * HD;
  float acc[NE];
#pragma unroll
  for (int e = 0; e < NE; ++e) acc[e] = 0.f;
  for (int h = lane; h < HD; h += 64) {
    float xv = xr[h];
#pragma unroll
    for (int e = 0; e < NE; ++e) acc[e] += xv * gw[e * HD + h];
  }
#pragma unroll
  for (int e = 0; e < NE; ++e) {
    float v = acc[e];
#pragma unroll
    for (int s = 32; s > 0; s >>= 1) v += __shfl_xor(v, s, 64);
    acc[e] = v;
  }
  float mx = acc[0];
#pragma unroll
  for (int e = 1; e < NE; ++e) mx = fmaxf(mx, acc[e]);
  float p[NE]; float sum = 0.f;
#pragma unroll
  for (int e = 0; e < NE; ++e) { p[e] = __expf(acc[e] - mx); sum += p[e]; }
  float inv = 1.f / sum;
#pragma unroll
  for (int e = 0; e < NE; ++e) p[e] *= inv;
  unsigned chosen = 0;
#pragma unroll
  for (int k = 0; k < 4; ++k) {
    int bi = 0; float bv = -1.f;
#pragma unroll
    for (int e = 0; e < NE; ++e) {
      bool ok = !((chosen >> e) & 1) && (p[e] > bv);
      bv = ok ? p[e] : bv;
      bi = ok ? e : bi;
    }
    chosen |= 1u << bi;
  }
  if (lane < NE)
    dense_w[t * NE + lane] = ((chosen >> lane) & 1) ? p[lane] : 0.f;
}

// ---------------- stable per-group token lists ------------------------------
__global__ void build_lists(const float* __restrict__ dense_w, int* __restrict__ tok,
                            float* __restrict__ scale, int* __restrict__ counts) {
  int g = blockIdx.x;
  int lane = threadIdx.x;  // blockDim = 64
  if (g >= NE) {
    for (int i = lane; i < TT; i += 64) { tok[g * TT + i] = i; scale[g * TT + i] = 1.f; }
    if (lane == 0) counts[g] = TT;
    return;
  }
  int base = 0;
  for (int c0 = 0; c0 < TT; c0 += 64) {
    int t = c0 + lane;
    float w = dense_w[t * NE + g];
    bool pred = w > 0.f;
    unsigned long long b = __ballot(pred);
    if (pred) {
      int pos = base + __popcll(b & ((1ull << lane) - 1ull));
      tok[g * TT + pos] = t;
      scale[g * TT + pos] = w;
    }
    base += __popcll(b);
  }
  if (lane == 0) counts[g] = base;
}

// ---------------- prefix + compact work lists (one block, 512 thr) ----------
__global__ void prefix_kernel(const int* __restrict__ counts, int* __restrict__ rowOff,
                              int* __restrict__ work1, int* __restrict__ work2,
                              int* __restrict__ meta) {
  const int tid = threadIdx.x;
  auto NRB = [&](int g) { return (counts[g] + 127) >> 7; };  // 128-row blocks
  if (tid == 0) {
    int s = 0;
    for (int g = 0; g < NE; ++g) { rowOff[g] = s; s += counts[g]; }
    rowOff[16] = 4 * TT;
    rowOff[17] = 4 * TT + TT;
    int n1 = 0, n2 = 0;
    for (int g = 0; g < NG; ++g) { n1 += NRB(g) * CB1; n2 += NRB(g) * CB2; }
    meta[0] = n1; meta[1] = (n1 + 7) / 8;
    meta[2] = n2; meta[3] = (n2 + 7) / 8;
  }
  if (tid < NG * CB1) {
    int g = tid / CB1, cb = tid % CB1;
    int base = 0;
    for (int gg = 0; gg < g; ++gg) base += NRB(gg) * CB1;
    int n = NRB(g);
    base += cb * n;
    for (int r = 0; r < n; ++r) work1[base + r] = (g << 16) | (cb << 8) | r;
  }
  if (tid < NG * CB2) {
    int g = tid / CB2, cb = tid % CB2;
    int base = 0;
    for (int gg = 0; gg < g; ++gg) base += NRB(gg) * CB2;
    int n = NRB(g);
    base += cb * n;
    for (int r = 0; r < n; ++r) work2[base + r] = (g << 16) | (cb << 8) | r;
  }
}

// ---------------- prep: x fp32 -> bf16 --------------------------------------
__global__ void cvt_bf16_kernel(const float* __restrict__ in,
                                unsigned short* __restrict__ out, int n4) {
  int i = blockIdx.x * blockDim.x + threadIdx.x;
  if (i < n4) {
    f32x4 v = ((const f32x4*)in)[i];
    u16x4 h;
    h.x = f2bf(v.x); h.y = f2bf(v.y); h.z = f2bf(v.z); h.w = f2bf(v.w);
    ((u16x4*)out)[i] = h;
  }
}

// ============================================================================
// grouped GEMM 1: Abuf = silu(x Wg)*(x Wu)*w   BM=128 BN=64 BK=32
// A: bf16 via global_load_lds (XOR-swizzled source).
// B: fp32 [K][N] -> column-load 8k/thread -> cvt_pk -> ONE ds_write_b128 into
//    [n][16w] chunk-XOR layout. b128 + conflict-free on BOTH write and read.
// ============================================================================
__global__ __launch_bounds__(256, 4) void gemm1_v10(
    const unsigned short* __restrict__ xb,
    const float* __restrict__ w_gate, const float* __restrict__ w_up,
    const float* __restrict__ ws_gate, const float* __restrict__ ws_up,
    const int* __restrict__ tok, const float* __restrict__ scale,
    const int* __restrict__ counts, const int* __restrict__ rowOff,
    const int* __restrict__ work, const int* __restrict__ meta,
    unsigned short* __restrict__ Abuf) {
  const int nw = meta[0], per = meta[1];
  const int xcd = blockIdx.x & 7, slot = blockIdx.x >> 3;
  if (slot >= per) return;
  const int w = xcd * per + slot;
  if (w >= nw) return;
  const int e = work[w];
  const int g = e >> 16, cb = (e >> 8) & 255, rb = e & 255;
  const int count = counts[g];

  __shared__ __align__(16) unsigned short sA[2][128 * 32];
  __shared__ __align__(16) unsigned sG[2][64 * 16];   // [n][16 words] swz
  __shared__ __align__(16) unsigned sU[2][64 * 16];

  const int tid = threadIdx.x, lane = tid & 63, wid = tid >> 6;
  const int wr = (wid >> 1) * 64, wc = (wid & 1) * 32;

  // ---- A staging (gload16): per-lane global, wave-uniform LDS dest ----
  const int lr = lane >> 2, lc = lane & 3;
  const int ra0 = wid * 32 + lr, ra1 = wid * 32 + 16 + lr;
  int gi0 = rb * 128 + ra0, gi1 = rb * 128 + ra1;
  int t0 = (gi0 < count) ? tok[g * TT + gi0] : 0;
  int t1 = (gi1 < count) ? tok[g * TT + gi1] : 0;
  const unsigned short* aG0 = xb + (size_t)t0 * HD + ((lc ^ ((ra0 >> 1) & 3)) * 8);
  const unsigned short* aG1 = xb + (size_t)t1 * HD + ((lc ^ ((ra1 >> 1) & 3)) * 8);

  // ---- B staging: thread = column n (tid&63), k-chunk kc (tid>>6) ----
  const int bn = tid & 63, kc = tid >> 6;   // kc in 0..3 (8 k each)
  const float *Bg, *Bu; size_t ldb; int bcol0;
  if (g < NE) {
    size_t o = (size_t)g * HD * FD;
    Bg = w_gate + o; Bu = w_up + o; ldb = FD; bcol0 = cb * 64;
  } else {
    Bg = ws_gate; Bu = ws_up; ldb = 2 * FD; bcol0 = (g - NE) * FD + cb * 64;
  }
  const float* gp = Bg + (size_t)(8 * kc) * ldb + bcol0 + bn;
  const float* up = Bu + (size_t)(8 * kc) * ldb + bcol0 + bn;
  const int bwa = bn * 16 + (((kc ^ ((bn >> 2) & 3))) << 2);  // b128 word addr

  const f32x4 fz = {0.f, 0.f, 0.f, 0.f};
  f32x4 accg[4][2], accu[4][2];
#pragma unroll
  for (int m = 0; m < 4; ++m)
#pragma unroll
    for (int n = 0; n < 2; ++n) { accg[m][n] = fz; accu[m][n] = fz; }

  float gv[8], uv[8];

  auto STAGEA = [&](int bu, int s) {
    size_t ko = (size_t)s * 32;
    gload16(aG0 + ko, &sA[bu][wid * 1024]);
    gload16(aG1 + ko, &sA[bu][wid * 1024 + 512]);
  };
  auto LOADB = [&](int s) {
#pragma unroll
    for (int j = 0; j < 8; ++j) {
      size_t o = (size_t)(32 * s + j) * ldb;
      gv[j] = gp[o];
      uv[j] = up[o];
    }
  };
  auto STOREB = [&](int bu) {
    u32x4 wg_, wu_;
#pragma unroll
    for (int j = 0; j < 4; ++j) {
      wg_[j] = cvt_pk(gv[2 * j], gv[2 * j + 1]);
      wu_[j] = cvt_pk(uv[2 * j], uv[2 * j + 1]);
    }
    *(u32x4*)&sG[bu][bwa] = wg_;
    *(u32x4*)&sU[bu][bwa] = wu_;
  };

  auto COMPUTE = [&](int bu) {
    const int ksel = lane >> 4;
    short8 av[4], bg[2], bv[2];
#pragma unroll
    for (int n = 0; n < 2; ++n) {
      int c = wc + n * 16 + (lane & 15);
      int idx = c * 16 + ((ksel ^ ((c >> 2) & 3)) << 2);
      bg[n] = __builtin_bit_cast(short8, *(const u32x4*)&sG[bu][idx]);
      bv[n] = __builtin_bit_cast(short8, *(const u32x4*)&sU[bu][idx]);
    }
#pragma unroll
    for (int m = 0; m < 4; ++m) {
      int r = wr + m * 16 + (lane & 15);
      av[m] = *(const short8*)&sA[bu][r * 32 + ((ksel ^ ((r >> 1) & 3)) << 3)];
    }
#pragma unroll
    for (int m = 0; m < 4; ++m)
#pragma unroll
      for (int n = 0; n < 2; ++n) {
        accg[m][n] = mfma16(av[m], bg[n], accg[m][n]);
        accu[m][n] = mfma16(av[m], bv[n], accu[m][n]);
      }
  };

  const int NK = HD / 32;  // 64
  LOADB(0);
  STAGEA(0, 0);
  STOREB(0);
  LOADB(1);
  __syncthreads();
#pragma unroll 1
  for (int s = 0; s < NK; ++s) {
    int bu = s & 1;
    if (s + 1 < NK) {
      STAGEA(bu ^ 1, s + 1);
      STOREB(bu ^ 1);           // consumes LOADB(s+1): full-step cover
    }
    if (s + 2 < NK) LOADB(s + 2);
    COMPUTE(bu);
    __syncthreads();
  }

  const int rowBase = rowOff[g] + rb * 128;
#pragma unroll
  for (int m = 0; m < 4; ++m)
#pragma unroll
    for (int r = 0; r < 4; ++r) {
      int rl = wr + m * 16 + ((lane >> 4) << 2) + r;
      int gi = rb * 128 + rl;
      if (gi < count) {
        float sc = scale[g * TT + gi];
#pragma unroll
        for (int n = 0; n < 2; ++n) {
          int cl = wc + n * 16 + (lane & 15);
          float gvv = accg[m][n][r], uvv = accu[m][n][r];
          float a = gvv / (1.f + __expf(-gvv)) * uvv * sc;
          Abuf[(size_t)(rowBase + rl) * FD + cb * 64 + cl] = f2bf(a);
        }
      }
    }
}

// ============================================================================
// grouped GEMM 2: out[tok] += Abuf @ Wdown   BM=128 BN=128 BK=32
// Same both-sides-b128 conflict-free B staging ([n][16w], n=tid&127).
// ============================================================================
__global__ __launch_bounds__(256, 4) void gemm2_v10(
    const unsigned short* __restrict__ Abuf,
    const float* __restrict__ w_down, const float* __restrict__ ws_down,
    const int* __restrict__ tok, const int* __restrict__ counts,
    const int* __restrict__ rowOff, const int* __restrict__ work,
    const int* __restrict__ meta, float* __restrict__ out) {
  const int nw = meta[2], per = meta[3];
  const int xcd = blockIdx.x & 7, slot = blockIdx.x >> 3;
  if (slot >= per) return;
  const int w = xcd * per + slot;
  if (w >= nw) return;
  const int e = work[w];
  const int g = e >> 16, cb = (e >> 8) & 255, rb = e & 255;
  const int count = counts[g];

  __shared__ __align__(16) unsigned short sA[2][128 * 32];
  __shared__ __align__(16) unsigned sB[2][128 * 16];  // [n][16 words] swz

  const int tid = threadIdx.x, lane = tid & 63, wid = tid >> 6;
  const int wr = (wid >> 1) * 64, wc = (wid & 1) * 64;

  const int rowBase = rowOff[g] + rb * 128;

  // ---- A staging (gload16) ----
  const int lr = lane >> 2, lc = lane & 3;
  const int ra0 = wid * 32 + lr, ra1 = wid * 32 + 16 + lr;
  const unsigned short* aG0 =
      Abuf + (size_t)(rowBase + ra0) * FD + ((lc ^ ((ra0 >> 1) & 3)) * 8);
  const unsigned short* aG1 =
      Abuf + (size_t)(rowBase + ra1) * FD + ((lc ^ ((ra1 >> 1) & 3)) * 8);

  // ---- B staging: thread = column n (tid&127), k-half kc2 (tid>>7) ----
  const int bn = tid & 127, kc2 = tid >> 7;   // kc2 in 0..1 (16 k each)
  const float* bp;
  if (g < NE)
    bp = w_down + (size_t)g * FD * HD + (size_t)(16 * kc2) * HD + cb * 128 + bn;
  else
    bp = ws_down + (size_t)((g - NE) * FD + 16 * kc2) * HD + cb * 128 + bn;
  const int kpa = 2 * kc2, kpb = 2 * kc2 + 1;
  const int bwa0 = bn * 16 + ((kpa ^ ((bn >> 2) & 3)) << 2);
  const int bwa1 = bn * 16 + ((kpb ^ ((bn >> 2) & 3)) << 2);

  const f32x4 fz = {0.f, 0.f, 0.f, 0.f};
  f32x4 acc[4][4];
#pragma unroll
  for (int m = 0; m < 4; ++m)
#pragma unroll
    for (int n = 0; n < 4; ++n) acc[m][n] = fz;

  float bvf[16];

  auto STAGEA = [&](int bu, int s) {
    size_t ko = (size_t)s * 32;
    gload16(aG0 + ko, &sA[bu][wid * 1024]);
    gload16(aG1 + ko, &sA[bu][wid * 1024 + 512]);
  };
  auto LOADB = [&](int s) {
#pragma unroll
    for (int j = 0; j < 16; ++j)
      bvf[j] = bp[(size_t)(32 * s + j) * HD];
  };
  auto STOREB = [&](int bu) {
    u32x4 w0, w1;
#pragma unroll
    for (int j = 0; j < 4; ++j) {
      w0[j] = cvt_pk(bvf[2 * j], bvf[2 * j + 1]);
      w1[j] = cvt_pk(bvf[8 + 2 * j], bvf[9 + 2 * j]);
    }
    *(u32x4*)&sB[bu][bwa0] = w0;
    *(u32x4*)&sB[bu][bwa1] = w1;
  };

  auto COMPUTE = [&](int bu) {
    const int ksel = lane >> 4;
    short8 av[4], bv[4];
#pragma unroll
    for (int n = 0; n < 4; ++n) {
      int c = wc + n * 16 + (lane & 15);
      int idx = c * 16 + ((ksel ^ ((c >> 2) & 3)) << 2);
      bv[n] = __builtin_bit_cast(short8, *(const u32x4*)&sB[bu][idx]);
    }
#pragma unroll
    for (int m = 0; m < 4; ++m) {
      int r = wr + m * 16 + (lane & 15);
      av[m] = *(const short8*)&sA[bu][r * 32 + ((ksel ^ ((r >> 1) & 3)) << 3)];
    }
#pragma unroll
    for (int m = 0; m < 4; ++m)
#pragma unroll
      for (int n = 0; n < 4; ++n) acc[m][n] = mfma16(av[m], bv[n], acc[m][n]);
  };

  const int NK = FD / 32;  // 44
  LOADB(0);
  STAGEA(0, 0);
  STOREB(0);
  LOADB(1);
  __syncthreads();
#pragma unroll 1
  for (int s = 0; s < NK; ++s) {
    int bu = s & 1;
    if (s + 1 < NK) {
      STAGEA(bu ^ 1, s + 1);
      STOREB(bu ^ 1);
    }
    if (s + 2 < NK) LOADB(s + 2);
    COMPUTE(bu);
    __syncthreads();
  }

#pragma unroll
  for (int m = 0; m < 4; ++m)
#pragma unroll
    for (int r = 0; r < 4; ++r) {
      int rl = wr + m * 16 + ((lane >> 4) << 2) + r;
      int gi = rb * 128 + rl;
      if (gi < count) {
        int t = tok[g * TT + gi];
        float* op = out + (size_t)t * HD + cb * 128;
#pragma unroll
        for (int n = 0; n < 4; ++n)
          atomicAdd(op + wc + n * 16 + (lane & 15), acc[m][n][r]);
      }
    }
}

// ---------------------------------------------------------------------------
extern "C" void kernel_launch(void* const* d_in, const int* in_sizes, int n_in,
                              void* d_out, int out_size, void* d_ws, size_t ws_size,
                              hipStream_t stream) {
  const float* x      = (const float*)d_in[0];
  const float* gw     = (const float*)d_in[1];
  const float* w_gate = (const float*)d_in[2];
  const float* w_up   = (const float*)d_in[3];
  const float* w_down = (const float*)d_in[4];
  const float* wsg    = (const float*)d_in[5];
  const float* wsu    = (const float*)d_in[6];
  const float* wsd    = (const float*)d_in[7];
  float* out = (float*)d_out;

  char* ws = (char*)d_ws;
  float* dense_w = (float*)(ws);                       // 128KB
  int*   tok     = (int*)(ws + (140 << 10));
  float* scale   = (float*)(ws + (290 << 10));
  int*   counts  = (int*)(ws + (440 << 10));
  int*   rowOff  = (int*)(ws + (441 << 10));
  int*   work1   = (int*)(ws + (444 << 10));
  int*   work2   = (int*)(ws + (456 << 10));
  int*   meta    = (int*)(ws + (464 << 10));
  unsigned short* Abuf = (unsigned short*)(ws + (1ull  << 20));   // 34.6MB
  unsigned short* xb   = (unsigned short*)(ws + (36ull << 20));   // 8MB

  hipMemsetAsync(d_out, 0, (size_t)out_size * sizeof(float), stream);
  gate_kernel<<<TT / 4, 256, 0, stream>>>(x, gw, dense_w);
  build_lists<<<NG, 64, 0, stream>>>(dense_w, tok, scale, counts);
  prefix_kernel<<<1, 512, 0, stream>>>(counts, rowOff, work1, work2, meta);
  cvt_bf16_kernel<<<(TT * HD / 4 + 255) / 256, 256, 0, stream>>>(x, xb, TT * HD / 4);

  gemm1_v10<<<MAXW1, 256, 0, stream>>>(
      xb, w_gate, w_up, wsg, wsu, tok, scale, counts, rowOff, work1, meta, Abuf);
  gemm2_v10<<<MAXW2, 256, 0, stream>>>(
      Abuf, w_down, wsd, tok, counts, rowOff, work2, meta, out);
}

// Round 11
// 537.213 us; speedup vs baseline: 3.4782x; 3.4782x over previous
//
#include <hip/hip_runtime.h>

#define TT 2048     // tokens
#define HD 2048     // hidden dim
#define FD 1408     // expert intermediate
#define NE 16       // routed experts
#define NG 18       // routed + 2 shared pseudo-experts

typedef __attribute__((ext_vector_type(4))) float f32x4;
typedef __attribute__((ext_vector_type(8))) short short8;
typedef __attribute__((ext_vector_type(8))) __bf16 bf16x8;
typedef __attribute__((ext_vector_type(4))) unsigned short u16x4;
typedef __attribute__((ext_vector_type(8))) unsigned short u16x8;
typedef __attribute__((ext_vector_type(2))) unsigned int u32x2;

__device__ __forceinline__ unsigned short f2bf(float f) {
  unsigned u = __builtin_bit_cast(unsigned, f);
  u += 0x7fffu + ((u >> 16) & 1u);   // RNE
  return (unsigned short)(u >> 16);
}
// packed 2xf32 -> 2xbf16 via native casts (compiler emits v_cvt_pk_bf16_f32)
__device__ __forceinline__ unsigned pk2(float lo, float hi) {
  unsigned short a = __builtin_bit_cast(unsigned short, (__bf16)lo);
  unsigned short b = __builtin_bit_cast(unsigned short, (__bf16)hi);
  return (unsigned)a | ((unsigned)b << 16);
}

template <typename T>
__device__ __forceinline__ auto mfma_try(T a, T b, f32x4 c, int)
    -> decltype(__builtin_amdgcn_mfma_f32_16x16x32_bf16(a, b, c, 0, 0, 0)) {
  return __builtin_amdgcn_mfma_f32_16x16x32_bf16(a, b, c, 0, 0, 0);
}
template <typename T, typename BV = bf16x8>
__device__ __forceinline__ f32x4 mfma_try(T a, T b, f32x4 c, long) {
  BV aa = __builtin_bit_cast(BV, a);
  BV bb = __builtin_bit_cast(BV, b);
  return __builtin_amdgcn_mfma_f32_16x16x32_bf16(aa, bb, c, 0, 0, 0);
}
__device__ __forceinline__ f32x4 mfma16(short8 a, short8 b, f32x4 c) {
  return mfma_try(a, b, c, 0);
}

// async 16B global->LDS (linear dest: wave base + lane*16)
__device__ __forceinline__ void gload16(const void* g, void* l) {
  __builtin_amdgcn_global_load_lds(
      (const __attribute__((address_space(1))) void*)g,
      (__attribute__((address_space(3))) void*)l, 16, 0, 0);
}

#define CB1 (FD / 64)               // 22 column-blocks, gemm1
#define CB2 (HD / 128)              // 16 column-blocks, gemm2
#define MAXW1 2464
#define MAXW2 1792

// ---------------- gate: logits -> softmax -> top4 -> dense weights ----------
__global__ void gate_kernel(const float* __restrict__ x, const float* __restrict__ gw,
                            float* __restrict__ dense_w) {
  int wid = threadIdx.x >> 6;
  int lane = threadIdx.x & 63;
  int t = blockIdx.x * 4 + wid;
  if (t >= TT) return;
  const float* xr = x + (size_t)t * HD;
  float acc[NE];
#pragma unroll
  for (int e = 0; e < NE; ++e) acc[e] = 0.f;
  for (int h = lane; h < HD; h += 64) {
    float xv = xr[h];
#pragma unroll
    for (int e = 0; e < NE; ++e) acc[e] += xv * gw[e * HD + h];
  }
#pragma unroll
  for (int e = 0; e < NE; ++e) {
    float v = acc[e];
#pragma unroll
    for (int s = 32; s > 0; s >>= 1) v += __shfl_xor(v, s, 64);
    acc[e] = v;
  }
  float mx = acc[0];
#pragma unroll
  for (int e = 1; e < NE; ++e) mx = fmaxf(mx, acc[e]);
  float p[NE]; float sum = 0.f;
#pragma unroll
  for (int e = 0; e < NE; ++e) { p[e] = __expf(acc[e] - mx); sum += p[e]; }
  float inv = 1.f / sum;
#pragma unroll
  for (int e = 0; e < NE; ++e) p[e] *= inv;
  unsigned chosen = 0;
#pragma unroll
  for (int k = 0; k < 4; ++k) {
    int bi = 0; float bv = -1.f;
#pragma unroll
    for (int e = 0; e < NE; ++e) {
      bool ok = !((chosen >> e) & 1) && (p[e] > bv);
      bv = ok ? p[e] : bv;
      bi = ok ? e : bi;
    }
    chosen |= 1u << bi;
  }
  if (lane < NE)
    dense_w[t * NE + lane] = ((chosen >> lane) & 1) ? p[lane] : 0.f;
}

// ---------------- stable per-group token lists ------------------------------
__global__ void build_lists(const float* __restrict__ dense_w, int* __restrict__ tok,
                            float* __restrict__ scale, int* __restrict__ counts) {
  int g = blockIdx.x;
  int lane = threadIdx.x;  // blockDim = 64
  if (g >= NE) {
    for (int i = lane; i < TT; i += 64) { tok[g * TT + i] = i; scale[g * TT + i] = 1.f; }
    if (lane == 0) counts[g] = TT;
    return;
  }
  int base = 0;
  for (int c0 = 0; c0 < TT; c0 += 64) {
    int t = c0 + lane;
    float w = dense_w[t * NE + g];
    bool pred = w > 0.f;
    unsigned long long b = __ballot(pred);
    if (pred) {
      int pos = base + __popcll(b & ((1ull << lane) - 1ull));
      tok[g * TT + pos] = t;
      scale[g * TT + pos] = w;
    }
    base += __popcll(b);
  }
  if (lane == 0) counts[g] = base;
}

// ---------------- prefix + compact work lists (one block, 512 thr) ----------
__global__ void prefix_kernel(const int* __restrict__ counts, int* __restrict__ rowOff,
                              int* __restrict__ work1, int* __restrict__ work2,
                              int* __restrict__ meta) {
  const int tid = threadIdx.x;
  auto NRB = [&](int g) { return (counts[g] + 127) >> 7; };  // 128-row blocks
  if (tid == 0) {
    int s = 0;
    for (int g = 0; g < NE; ++g) { rowOff[g] = s; s += counts[g]; }
    rowOff[16] = 4 * TT;
    rowOff[17] = 4 * TT + TT;
    int n1 = 0, n2 = 0;
    for (int g = 0; g < NG; ++g) { n1 += NRB(g) * CB1; n2 += NRB(g) * CB2; }
    meta[0] = n1; meta[1] = (n1 + 7) / 8;
    meta[2] = n2; meta[3] = (n2 + 7) / 8;
  }
  if (tid < NG * CB1) {
    int g = tid / CB1, cb = tid % CB1;
    int base = 0;
    for (int gg = 0; gg < g; ++gg) base += NRB(gg) * CB1;
    int n = NRB(g);
    base += cb * n;
    for (int r = 0; r < n; ++r) work1[base + r] = (g << 16) | (cb << 8) | r;
  }
  if (tid < NG * CB2) {
    int g = tid / CB2, cb = tid % CB2;
    int base = 0;
    for (int gg = 0; gg < g; ++gg) base += NRB(gg) * CB2;
    int n = NRB(g);
    base += cb * n;
    for (int r = 0; r < n; ++r) work2[base + r] = (g << 16) | (cb << 8) | r;
  }
}

// ---------------- prep: x fp32 -> bf16 --------------------------------------
__global__ void cvt_bf16_kernel(const float* __restrict__ in,
                                unsigned short* __restrict__ out, int n4) {
  int i = blockIdx.x * blockDim.x + threadIdx.x;
  if (i < n4) {
    f32x4 v = ((const f32x4*)in)[i];
    u16x4 h;
    h.x = f2bf(v.x); h.y = f2bf(v.y); h.z = f2bf(v.z); h.w = f2bf(v.w);
    ((u16x4*)out)[i] = h;
  }
}

// ============================================================================
// grouped GEMM 1: Abuf = silu(x Wg)*(x Wu)*w   BM=128 BN=64 BK=32
// A: bf16 via global_load_lds.  B: native fp32 [K][N], reg-staged cvt->LDS.
// Write order permuted (jj = j0 ^ ((nq>>2)&1)) -> 2-way (free) LDS writes.
// ============================================================================
__global__ __launch_bounds__(256, 4) void gemm1_v11(
    const unsigned short* __restrict__ xb,
    const float* __restrict__ w_gate, const float* __restrict__ w_up,
    const float* __restrict__ ws_gate, const float* __restrict__ ws_up,
    const int* __restrict__ tok, const float* __restrict__ scale,
    const int* __restrict__ counts, const int* __restrict__ rowOff,
    const int* __restrict__ work, const int* __restrict__ meta,
    unsigned short* __restrict__ Abuf) {
  const int nw = meta[0], per = meta[1];
  const int xcd = blockIdx.x & 7, slot = blockIdx.x >> 3;
  if (slot >= per) return;
  const int w = xcd * per + slot;
  if (w >= nw) return;
  const int e = work[w];
  const int g = e >> 16, cb = (e >> 8) & 255, rb = e & 255;
  const int count = counts[g];

  __shared__ __align__(16) unsigned short sA[2][128 * 32];
  __shared__ __align__(16) unsigned short sG[2][64 * 32];
  __shared__ __align__(16) unsigned short sU[2][64 * 32];

  const int tid = threadIdx.x, lane = tid & 63, wid = tid >> 6;
  const int wr = (wid >> 1) * 64, wc = (wid & 1) * 32;

  // ---- A staging (gload16): per-lane global, wave-uniform LDS dest ----
  const int lr = lane >> 2, lc = lane & 3;
  const int ra0 = wid * 32 + lr, ra1 = wid * 32 + 16 + lr;
  int gi0 = rb * 128 + ra0, gi1 = rb * 128 + ra1;
  int t0 = (gi0 < count) ? tok[g * TT + gi0] : 0;
  int t1 = (gi1 < count) ? tok[g * TT + gi1] : 0;
  const unsigned short* aG0 = xb + (size_t)t0 * HD + ((lc ^ ((ra0 >> 1) & 3)) * 8);
  const unsigned short* aG1 = xb + (size_t)t1 * HD + ((lc ^ ((ra1 >> 1) & 3)) * 8);

  // ---- B staging (reg): thread = k-pair kp (rows 2kp,2kp+1) x 4 cols ----
  const int kp = tid >> 4, nq = tid & 15;
  const int n0 = nq * 4;
  const float *Bg, *Bu; size_t ldb; int bcol0;
  if (g < NE) {
    size_t o = (size_t)g * HD * FD;
    Bg = w_gate + o; Bu = w_up + o; ldb = FD; bcol0 = cb * 64;
  } else {
    Bg = ws_gate; Bu = ws_up; ldb = 2 * FD; bcol0 = (g - NE) * FD + cb * 64;
  }
  const float* gp = Bg + (size_t)(2 * kp) * ldb + bcol0 + n0;
  const float* up = Bu + (size_t)(2 * kp) * ldb + bcol0 + n0;
  // LDS word indices for the 4 n's (chunk-XOR G(n) = (n>>2)&3 = nq&3)
  int bwi[4];
#pragma unroll
  for (int j = 0; j < 4; ++j) {
    int n = n0 + j;
    bwi[j] = n * 16 + (((kp >> 2) ^ ((n >> 2) & 3)) << 2) + (kp & 3);
  }
  const int bperm = (nq >> 2) & 1;

  const f32x4 fz = {0.f, 0.f, 0.f, 0.f};
  f32x4 accg[4][2], accu[4][2];
#pragma unroll
  for (int m = 0; m < 4; ++m)
#pragma unroll
    for (int n = 0; n < 2; ++n) { accg[m][n] = fz; accu[m][n] = fz; }

  f32x4 g0, g1, u0, u1;

  auto STAGEA = [&](int bu, int s) {
    size_t ko = (size_t)s * 32;
    gload16(aG0 + ko, &sA[bu][wid * 1024]);
    gload16(aG1 + ko, &sA[bu][wid * 1024 + 512]);
  };
  auto LOADB = [&](int s) {
    const float* _g = gp + (size_t)s * 32 * ldb;
    const float* _u = up + (size_t)s * 32 * ldb;
    g0 = *(const f32x4*)_g; g1 = *(const f32x4*)(_g + ldb);
    u0 = *(const f32x4*)_u; u1 = *(const f32x4*)(_u + ldb);
  };
  auto STOREB = [&](int bu) {
    unsigned* gw_ = (unsigned*)sG[bu];
    unsigned* uw_ = (unsigned*)sU[bu];
#pragma unroll
    for (int j0 = 0; j0 < 4; ++j0) {
      int jj = j0 ^ bperm;
      gw_[bwi[jj]] = pk2(g0[jj], g1[jj]);
      uw_[bwi[jj]] = pk2(u0[jj], u1[jj]);
    }
  };

  auto COMPUTE = [&](int bu) {
    const int ksel = lane >> 4;
    short8 av[4], bg[2], bv[2];
#pragma unroll
    for (int n = 0; n < 2; ++n) {
      int c = wc + n * 16 + (lane & 15);
      int idx = c * 32 + ((ksel ^ ((c >> 2) & 3)) << 3);
      bg[n] = *(const short8*)&sG[bu][idx];
      bv[n] = *(const short8*)&sU[bu][idx];
    }
#pragma unroll
    for (int m = 0; m < 4; ++m) {
      int r = wr + m * 16 + (lane & 15);
      av[m] = *(const short8*)&sA[bu][r * 32 + ((ksel ^ ((r >> 1) & 3)) << 3)];
    }
#pragma unroll
    for (int m = 0; m < 4; ++m)
#pragma unroll
      for (int n = 0; n < 2; ++n) {
        accg[m][n] = mfma16(av[m], bg[n], accg[m][n]);
        accu[m][n] = mfma16(av[m], bv[n], accu[m][n]);
      }
  };

  const int NK = HD / 32;  // 64
  LOADB(0);
  STAGEA(0, 0);
  STOREB(0);
  LOADB(1);
  __syncthreads();
#pragma unroll 1
  for (int s = 0; s < NK; ++s) {
    int bu = s & 1;
    if (s + 1 < NK) STAGEA(bu ^ 1, s + 1);
    COMPUTE(bu);
    if (s + 1 < NK) STOREB(bu ^ 1);
    if (s + 2 < NK) LOADB(s + 2);
    __syncthreads();
  }

  const int rowBase = rowOff[g] + rb * 128;
#pragma unroll
  for (int m = 0; m < 4; ++m)
#pragma unroll
    for (int r = 0; r < 4; ++r) {
      int rl = wr + m * 16 + ((lane >> 4) << 2) + r;
      int gi = rb * 128 + rl;
      if (gi < count) {
        float sc = scale[g * TT + gi];
#pragma unroll
        for (int n = 0; n < 2; ++n) {
          int cl = wc + n * 16 + (lane & 15);
          float gv = accg[m][n][r], uv = accu[m][n][r];
          float a = gv / (1.f + __expf(-gv)) * uv * sc;
          Abuf[(size_t)(rowBase + rl) * FD + cb * 64 + cl] = f2bf(a);
        }
      }
    }
}

// ============================================================================
// grouped GEMM 2: out[tok] += Abuf @ Wdown   BM=128 BN=128 BK=32
// A: bf16 Abuf via global_load_lds.  B: native fp32 [F][H], reg-staged cvt.
// G(n) = ((n>>2)^(n>>4))&3 both sides + permuted write order.
// ============================================================================
__global__ __launch_bounds__(256, 4) void gemm2_v11(
    const unsigned short* __restrict__ Abuf,
    const float* __restrict__ w_down, const float* __restrict__ ws_down,
    const int* __restrict__ tok, const int* __restrict__ counts,
    const int* __restrict__ rowOff, const int* __restrict__ work,
    const int* __restrict__ meta, float* __restrict__ out) {
  const int nw = meta[2], per = meta[3];
  const int xcd = blockIdx.x & 7, slot = blockIdx.x >> 3;
  if (slot >= per) return;
  const int w = xcd * per + slot;
  if (w >= nw) return;
  const int e = work[w];
  const int g = e >> 16, cb = (e >> 8) & 255, rb = e & 255;
  const int count = counts[g];

  __shared__ __align__(16) unsigned short sA[2][128 * 32];
  __shared__ __align__(16) unsigned short sB[2][128 * 32];

  const int tid = threadIdx.x, lane = tid & 63, wid = tid >> 6;
  const int wr = (wid >> 1) * 64, wc = (wid & 1) * 64;

  const int rowBase = rowOff[g] + rb * 128;

  // ---- A staging (gload16) ----
  const int lr = lane >> 2, lc = lane & 3;
  const int ra0 = wid * 32 + lr, ra1 = wid * 32 + 16 + lr;
  const unsigned short* aG0 =
      Abuf + (size_t)(rowBase + ra0) * FD + ((lc ^ ((ra0 >> 1) & 3)) * 8);
  const unsigned short* aG1 =
      Abuf + (size_t)(rowBase + ra1) * FD + ((lc ^ ((ra1 >> 1) & 3)) * 8);

  // ---- B staging (reg): thread = 4 k-rows (pairs 2kg,2kg+1) x 4 cols ----
  const int kg = tid >> 5, nq = tid & 31;
  const int n0 = nq * 4;
  const float* bp;
  if (g < NE)
    bp = w_down + (size_t)g * FD * HD + (size_t)(4 * kg) * HD + cb * 128 + n0;
  else
    bp = ws_down + (size_t)((g - NE) * FD + 4 * kg) * HD + cb * 128 + n0;
  int bwi[4];
#pragma unroll
  for (int j = 0; j < 4; ++j) {
    int n = n0 + j;
    bwi[j] = n * 16 + (((kg >> 1) ^ (((n >> 2) ^ (n >> 4)) & 3)) << 2) + ((2 * kg) & 3);
  }
  const int bperm = (nq >> 2) & 1;

  const f32x4 fz = {0.f, 0.f, 0.f, 0.f};
  f32x4 acc[4][4];
#pragma unroll
  for (int m = 0; m < 4; ++m)
#pragma unroll
    for (int n = 0; n < 4; ++n) acc[m][n] = fz;

  f32x4 b0, b1, b2, b3;

  auto STAGEA = [&](int bu, int s) {
    size_t ko = (size_t)s * 32;
    gload16(aG0 + ko, &sA[bu][wid * 1024]);
    gload16(aG1 + ko, &sA[bu][wid * 1024 + 512]);
  };
  auto LOADB = [&](int s) {
    const float* _b = bp + (size_t)s * 32 * HD;
    b0 = *(const f32x4*)_b;
    b1 = *(const f32x4*)(_b + HD);
    b2 = *(const f32x4*)(_b + 2 * HD);
    b3 = *(const f32x4*)(_b + 3 * HD);
  };
  auto STOREB = [&](int bu) {
    unsigned* bw_ = (unsigned*)sB[bu];
#pragma unroll
    for (int j0 = 0; j0 < 4; ++j0) {
      int jj = j0 ^ bperm;
      u32x2 v;
      v.x = pk2(b0[jj], b1[jj]);
      v.y = pk2(b2[jj], b3[jj]);
      *(u32x2*)&bw_[bwi[jj]] = v;
    }
  };

  auto COMPUTE = [&](int bu) {
    const int ksel = lane >> 4;
    short8 av[4], bv[4];
#pragma unroll
    for (int n = 0; n < 4; ++n) {
      int c = wc + n * 16 + (lane & 15);
      int idx = c * 32 + ((ksel ^ (((c >> 2) ^ (c >> 4)) & 3)) << 3);
      bv[n] = *(const short8*)&sB[bu][idx];
    }
#pragma unroll
    for (int m = 0; m < 4; ++m) {
      int r = wr + m * 16 + (lane & 15);
      av[m] = *(const short8*)&sA[bu][r * 32 + ((ksel ^ ((r >> 1) & 3)) << 3)];
    }
#pragma unroll
    for (int m = 0; m < 4; ++m)
#pragma unroll
      for (int n = 0; n < 4; ++n) acc[m][n] = mfma16(av[m], bv[n], acc[m][n]);
  };

  const int NK = FD / 32;  // 44
  LOADB(0);
  STAGEA(0, 0);
  STOREB(0);
  LOADB(1);
  __syncthreads();
#pragma unroll 1
  for (int s = 0; s < NK; ++s) {
    int bu = s & 1;
    if (s + 1 < NK) STAGEA(bu ^ 1, s + 1);
    COMPUTE(bu);
    if (s + 1 < NK) STOREB(bu ^ 1);
    if (s + 2 < NK) LOADB(s + 2);
    __syncthreads();
  }

#pragma unroll
  for (int m = 0; m < 4; ++m)
#pragma unroll
    for (int r = 0; r < 4; ++r) {
      int rl = wr + m * 16 + ((lane >> 4) << 2) + r;
      int gi = rb * 128 + rl;
      if (gi < count) {
        int t = tok[g * TT + gi];
        float* op = out + (size_t)t * HD + cb * 128;
#pragma unroll
        for (int n = 0; n < 4; ++n)
          atomicAdd(op + wc + n * 16 + (lane & 15), acc[m][n][r]);
      }
    }
}

// ---------------------------------------------------------------------------
extern "C" void kernel_launch(void* const* d_in, const int* in_sizes, int n_in,
                              void* d_out, int out_size, void* d_ws, size_t ws_size,
                              hipStream_t stream) {
  const float* x      = (const float*)d_in[0];
  const float* gw     = (const float*)d_in[1];
  const float* w_gate = (const float*)d_in[2];
  const float* w_up   = (const float*)d_in[3];
  const float* w_down = (const float*)d_in[4];
  const float* wsg    = (const float*)d_in[5];
  const float* wsu    = (const float*)d_in[6];
  const float* wsd    = (const float*)d_in[7];
  float* out = (float*)d_out;

  char* ws = (char*)d_ws;
  float* dense_w = (float*)(ws);                       // 128KB
  int*   tok     = (int*)(ws + (140 << 10));
  float* scale   = (float*)(ws + (290 << 10));
  int*   counts  = (int*)(ws + (440 << 10));
  int*   rowOff  = (int*)(ws + (441 << 10));
  int*   work1   = (int*)(ws + (444 << 10));
  int*   work2   = (int*)(ws + (456 << 10));
  int*   meta    = (int*)(ws + (464 << 10));
  unsigned short* Abuf = (unsigned short*)(ws + (1ull  << 20));   // 34.6MB
  unsigned short* xb   = (unsigned short*)(ws + (36ull << 20));   // 8MB

  hipMemsetAsync(d_out, 0, (size_t)out_size * sizeof(float), stream);
  gate_kernel<<<TT / 4, 256, 0, stream>>>(x, gw, dense_w);
  build_lists<<<NG, 64, 0, stream>>>(dense_w, tok, scale, counts);
  prefix_kernel<<<1, 512, 0, stream>>>(counts, rowOff, work1, work2, meta);
  cvt_bf16_kernel<<<(TT * HD / 4 + 255) / 256, 256, 0, stream>>>(x, xb, TT * HD / 4);

  gemm1_v11<<<MAXW1, 256, 0, stream>>>(
      xb, w_gate, w_up, wsg, wsu, tok, scale, counts, rowOff, work1, meta, Abuf);
  gemm2_v11<<<MAXW2, 256, 0, stream>>>(
      Abuf, w_down, wsd, tok, counts, rowOff, work2, meta, out);
}

// Round 12
// 489.817 us; speedup vs baseline: 3.8147x; 1.0968x over previous
//
#include <hip/hip_runtime.h>

#define TT 2048     // tokens
#define HD 2048     // hidden dim
#define FD 1408     // expert intermediate
#define NE 16       // routed experts
#define NG 18       // routed + 2 shared pseudo-experts

typedef __attribute__((ext_vector_type(4))) float f32x4;
typedef __attribute__((ext_vector_type(8))) short short8;
typedef __attribute__((ext_vector_type(8))) __bf16 bf16x8;
typedef __attribute__((ext_vector_type(4))) unsigned short u16x4;
typedef __attribute__((ext_vector_type(8))) unsigned short u16x8;
typedef __attribute__((ext_vector_type(2))) unsigned int u32x2;

__device__ __forceinline__ unsigned short f2bf(float f) {
  unsigned u = __builtin_bit_cast(unsigned, f);
  u += 0x7fffu + ((u >> 16) & 1u);   // RNE
  return (unsigned short)(u >> 16);
}
// packed 2xf32 -> 2xbf16, one VALU instruction (proven VALU win in v9)
__device__ __forceinline__ unsigned cvt_pk(float lo, float hi) {
  unsigned r;
  asm("v_cvt_pk_bf16_f32 %0, %1, %2" : "=v"(r) : "v"(lo), "v"(hi));
  return r;
}

template <typename T>
__device__ __forceinline__ auto mfma_try(T a, T b, f32x4 c, int)
    -> decltype(__builtin_amdgcn_mfma_f32_16x16x32_bf16(a, b, c, 0, 0, 0)) {
  return __builtin_amdgcn_mfma_f32_16x16x32_bf16(a, b, c, 0, 0, 0);
}
template <typename T, typename BV = bf16x8>
__device__ __forceinline__ f32x4 mfma_try(T a, T b, f32x4 c, long) {
  BV aa = __builtin_bit_cast(BV, a);
  BV bb = __builtin_bit_cast(BV, b);
  return __builtin_amdgcn_mfma_f32_16x16x32_bf16(aa, bb, c, 0, 0, 0);
}
__device__ __forceinline__ f32x4 mfma16(short8 a, short8 b, f32x4 c) {
  return mfma_try(a, b, c, 0);
}

// async 16B global->LDS (linear dest: wave base + lane*16)
__device__ __forceinline__ void gload16(const void* g, void* l) {
  __builtin_amdgcn_global_load_lds(
      (const __attribute__((address_space(1))) void*)g,
      (__attribute__((address_space(3))) void*)l, 16, 0, 0);
}

#define CB1 (FD / 64)               // 22 column-blocks, gemm1
#define CB2 (HD / 128)              // 16 column-blocks, gemm2
#define MAXW1 2464
#define MAXW2 1792

// ---------------- gate: logits -> softmax -> top4 -> dense weights ----------
__global__ void gate_kernel(const float* __restrict__ x, const float* __restrict__ gw,
                            float* __restrict__ dense_w) {
  int wid = threadIdx.x >> 6;
  int lane = threadIdx.x & 63;
  int t = blockIdx.x * 4 + wid;
  if (t >= TT) return;
  const float* xr = x + (size_t)t * HD;
  float acc[NE];
#pragma unroll
  for (int e = 0; e < NE; ++e) acc[e] = 0.f;
  for (int h = lane; h < HD; h += 64) {
    float xv = xr[h];
#pragma unroll
    for (int e = 0; e < NE; ++e) acc[e] += xv * gw[e * HD + h];
  }
#pragma unroll
  for (int e = 0; e < NE; ++e) {
    float v = acc[e];
#pragma unroll
    for (int s = 32; s > 0; s >>= 1) v += __shfl_xor(v, s, 64);
    acc[e] = v;
  }
  float mx = acc[0];
#pragma unroll
  for (int e = 1; e < NE; ++e) mx = fmaxf(mx, acc[e]);
  float p[NE]; float sum = 0.f;
#pragma unroll
  for (int e = 0; e < NE; ++e) { p[e] = __expf(acc[e] - mx); sum += p[e]; }
  float inv = 1.f / sum;
#pragma unroll
  for (int e = 0; e < NE; ++e) p[e] *= inv;
  unsigned chosen = 0;
#pragma unroll
  for (int k = 0; k < 4; ++k) {
    int bi = 0; float bv = -1.f;
#pragma unroll
    for (int e = 0; e < NE; ++e) {
      bool ok = !((chosen >> e) & 1) && (p[e] > bv);
      bv = ok ? p[e] : bv;
      bi = ok ? e : bi;
    }
    chosen |= 1u << bi;
  }
  if (lane < NE)
    dense_w[t * NE + lane] = ((chosen >> lane) & 1) ? p[lane] : 0.f;
}

// ---------------- stable per-group token lists ------------------------------
__global__ void build_lists(const float* __restrict__ dense_w, int* __restrict__ tok,
                            float* __restrict__ scale, int* __restrict__ counts) {
  int g = blockIdx.x;
  int lane = threadIdx.x;  // blockDim = 64
  if (g >= NE) {
    for (int i = lane; i < TT; i += 64) { tok[g * TT + i] = i; scale[g * TT + i] = 1.f; }
    if (lane == 0) counts[g] = TT;
    return;
  }
  int base = 0;
  for (int c0 = 0; c0 < TT; c0 += 64) {
    int t = c0 + lane;
    float w = dense_w[t * NE + g];
    bool pred = w > 0.f;
    unsigned long long b = __ballot(pred);
    if (pred) {
      int pos = base + __popcll(b & ((1ull << lane) - 1ull));
      tok[g * TT + pos] = t;
      scale[g * TT + pos] = w;
    }
    base += __popcll(b);
  }
  if (lane == 0) counts[g] = base;
}

// ---------------- prefix + compact work lists (one block, 512 thr) ----------
__global__ void prefix_kernel(const int* __restrict__ counts, int* __restrict__ rowOff,
                              int* __restrict__ work1, int* __restrict__ work2,
                              int* __restrict__ meta) {
  const int tid = threadIdx.x;
  auto NRB = [&](int g) { return (counts[g] + 127) >> 7; };  // 128-row blocks
  if (tid == 0) {
    int s = 0;
    for (int g = 0; g < NE; ++g) { rowOff[g] = s; s += counts[g]; }
    rowOff[16] = 4 * TT;
    rowOff[17] = 4 * TT + TT;
    int n1 = 0, n2 = 0;
    for (int g = 0; g < NG; ++g) { n1 += NRB(g) * CB1; n2 += NRB(g) * CB2; }
    meta[0] = n1; meta[1] = (n1 + 7) / 8;
    meta[2] = n2; meta[3] = (n2 + 7) / 8;
  }
  if (tid < NG * CB1) {
    int g = tid / CB1, cb = tid % CB1;
    int base = 0;
    for (int gg = 0; gg < g; ++gg) base += NRB(gg) * CB1;
    int n = NRB(g);
    base += cb * n;
    for (int r = 0; r < n; ++r) work1[base + r] = (g << 16) | (cb << 8) | r;
  }
  if (tid < NG * CB2) {
    int g = tid / CB2, cb = tid % CB2;
    int base = 0;
    for (int gg = 0; gg < g; ++gg) base += NRB(gg) * CB2;
    int n = NRB(g);
    base += cb * n;
    for (int r = 0; r < n; ++r) work2[base + r] = (g << 16) | (cb << 8) | r;
  }
}

// ---------------- prep: x fp32 -> bf16 --------------------------------------
__global__ void cvt_bf16_kernel(const float* __restrict__ in,
                                unsigned short* __restrict__ out, int n4) {
  int i = blockIdx.x * blockDim.x + threadIdx.x;
  if (i < n4) {
    f32x4 v = ((const f32x4*)in)[i];
    u16x4 h;
    h.x = f2bf(v.x); h.y = f2bf(v.y); h.z = f2bf(v.z); h.w = f2bf(v.w);
    ((u16x4*)out)[i] = h;
  }
}

// ============================================================================
// grouped GEMM 1: Abuf = silu(x Wg)*(x Wu)*w   BM=128 BN=64 BK=32
// A: bf16 via global_load_lds.
// B: fp32 [K][N] -> 16 dword loads (strided-n thread map) -> cvt_pk -> LDS.
//    Write bank span = 32 (lane bits 0,2,3,4,5) -> 2-way = free.
// ============================================================================
__global__ __launch_bounds__(256, 4) void gemm1_v12(
    const unsigned short* __restrict__ xb,
    const float* __restrict__ w_gate, const float* __restrict__ w_up,
    const float* __restrict__ ws_gate, const float* __restrict__ ws_up,
    const int* __restrict__ tok, const float* __restrict__ scale,
    const int* __restrict__ counts, const int* __restrict__ rowOff,
    const int* __restrict__ work, const int* __restrict__ meta,
    unsigned short* __restrict__ Abuf) {
  const int nw = meta[0], per = meta[1];
  const int xcd = blockIdx.x & 7, slot = blockIdx.x >> 3;
  if (slot >= per) return;
  const int w = xcd * per + slot;
  if (w >= nw) return;
  const int e = work[w];
  const int g = e >> 16, cb = (e >> 8) & 255, rb = e & 255;
  const int count = counts[g];

  __shared__ __align__(16) unsigned short sA[2][128 * 32];
  __shared__ __align__(16) unsigned short sG[2][64 * 32];
  __shared__ __align__(16) unsigned short sU[2][64 * 32];

  const int tid = threadIdx.x, lane = tid & 63, wid = tid >> 6;
  const int wr = (wid >> 1) * 64, wc = (wid & 1) * 32;

  // ---- A staging (gload16): per-lane global, wave-uniform LDS dest ----
  const int lr = lane >> 2, lc = lane & 3;
  const int ra0 = wid * 32 + lr, ra1 = wid * 32 + 16 + lr;
  int gi0 = rb * 128 + ra0, gi1 = rb * 128 + ra1;
  int t0 = (gi0 < count) ? tok[g * TT + gi0] : 0;
  int t1 = (gi1 < count) ? tok[g * TT + gi1] : 0;
  const unsigned short* aG0 = xb + (size_t)t0 * HD + ((lc ^ ((ra0 >> 1) & 3)) * 8);
  const unsigned short* aG1 = xb + (size_t)t1 * HD + ((lc ^ ((ra1 >> 1) & 3)) * 8);

  // ---- B staging: thread = k-pair kp (rows 2kp,2kp+1) x cols n = nq+16j ----
  const int kp = tid >> 4, nq = tid & 15;
  const float *Bg, *Bu; size_t ldb; int bcol0;
  if (g < NE) {
    size_t o = (size_t)g * HD * FD;
    Bg = w_gate + o; Bu = w_up + o; ldb = FD; bcol0 = cb * 64;
  } else {
    Bg = ws_gate; Bu = ws_up; ldb = 2 * FD; bcol0 = (g - NE) * FD + cb * 64;
  }
  const float* gp0 = Bg + (size_t)(2 * kp) * ldb + bcol0 + nq;
  const float* gp1 = gp0 + ldb;
  const float* up0 = Bu + (size_t)(2 * kp) * ldb + bcol0 + nq;
  const float* up1 = up0 + ldb;
  // LDS word index for column n = nq+16j: j-invariant chunk XOR
  const int bw0 = nq * 16 + (((kp >> 2) ^ ((nq >> 2) & 3)) << 2) + (kp & 3);
  // consecutive j: += 16*16 = 256 words

  const f32x4 fz = {0.f, 0.f, 0.f, 0.f};
  f32x4 accg[4][2], accu[4][2];
#pragma unroll
  for (int m = 0; m < 4; ++m)
#pragma unroll
    for (int n = 0; n < 2; ++n) { accg[m][n] = fz; accu[m][n] = fz; }

  float gv0[4], gv1[4], uv0[4], uv1[4];

  auto STAGEA = [&](int bu, int s) {
    size_t ko = (size_t)s * 32;
    gload16(aG0 + ko, &sA[bu][wid * 1024]);
    gload16(aG1 + ko, &sA[bu][wid * 1024 + 512]);
  };
  auto LOADB = [&](int s) {
    size_t o = (size_t)s * 32 * ldb;
#pragma unroll
    for (int j = 0; j < 4; ++j) {
      gv0[j] = gp0[o + 16 * j];
      gv1[j] = gp1[o + 16 * j];
      uv0[j] = up0[o + 16 * j];
      uv1[j] = up1[o + 16 * j];
    }
  };
  auto STOREB = [&](int bu) {
    unsigned* gw_ = (unsigned*)sG[bu];
    unsigned* uw_ = (unsigned*)sU[bu];
#pragma unroll
    for (int j = 0; j < 4; ++j) {
      gw_[bw0 + 256 * j] = cvt_pk(gv0[j], gv1[j]);
      uw_[bw0 + 256 * j] = cvt_pk(uv0[j], uv1[j]);
    }
  };

  auto COMPUTE = [&](int bu) {
    const int ksel = lane >> 4;
    short8 av[4], bg[2], bv[2];
#pragma unroll
    for (int n = 0; n < 2; ++n) {
      int c = wc + n * 16 + (lane & 15);
      int idx = c * 32 + ((ksel ^ ((c >> 2) & 3)) << 3);
      bg[n] = *(const short8*)&sG[bu][idx];
      bv[n] = *(const short8*)&sU[bu][idx];
    }
#pragma unroll
    for (int m = 0; m < 4; ++m) {
      int r = wr + m * 16 + (lane & 15);
      av[m] = *(const short8*)&sA[bu][r * 32 + ((ksel ^ ((r >> 1) & 3)) << 3)];
    }
#pragma unroll
    for (int m = 0; m < 4; ++m)
#pragma unroll
      for (int n = 0; n < 2; ++n) {
        accg[m][n] = mfma16(av[m], bg[n], accg[m][n]);
        accu[m][n] = mfma16(av[m], bv[n], accu[m][n]);
      }
  };

  const int NK = HD / 32;  // 64
  LOADB(0);
  STAGEA(0, 0);
  STOREB(0);
  LOADB(1);
  __syncthreads();
#pragma unroll 1
  for (int s = 0; s < NK; ++s) {
    int bu = s & 1;
    if (s + 1 < NK) STAGEA(bu ^ 1, s + 1);
    COMPUTE(bu);
    if (s + 1 < NK) STOREB(bu ^ 1);
    if (s + 2 < NK) LOADB(s + 2);
    __syncthreads();
  }

  const int rowBase = rowOff[g] + rb * 128;
#pragma unroll
  for (int m = 0; m < 4; ++m)
#pragma unroll
    for (int r = 0; r < 4; ++r) {
      int rl = wr + m * 16 + ((lane >> 4) << 2) + r;
      int gi = rb * 128 + rl;
      if (gi < count) {
        float sc = scale[g * TT + gi];
#pragma unroll
        for (int n = 0; n < 2; ++n) {
          int cl = wc + n * 16 + (lane & 15);
          float gvv = accg[m][n][r], uvv = accu[m][n][r];
          float a = gvv / (1.f + __expf(-gvv)) * uvv * sc;
          Abuf[(size_t)(rowBase + rl) * FD + cb * 64 + cl] = f2bf(a);
        }
      }
    }
}

// ============================================================================
// grouped GEMM 2: out[tok] += Abuf @ Wdown   BM=128 BN=128 BK=32
// Same strided-n mapping; b64 writes (exact 4-words/bank minimum).
// ============================================================================
__global__ __launch_bounds__(256, 4) void gemm2_v12(
    const unsigned short* __restrict__ Abuf,
    const float* __restrict__ w_down, const float* __restrict__ ws_down,
    const int* __restrict__ tok, const int* __restrict__ counts,
    const int* __restrict__ rowOff, const int* __restrict__ work,
    const int* __restrict__ meta, float* __restrict__ out) {
  const int nw = meta[2], per = meta[3];
  const int xcd = blockIdx.x & 7, slot = blockIdx.x >> 3;
  if (slot >= per) return;
  const int w = xcd * per + slot;
  if (w >= nw) return;
  const int e = work[w];
  const int g = e >> 16, cb = (e >> 8) & 255, rb = e & 255;
  const int count = counts[g];

  __shared__ __align__(16) unsigned short sA[2][128 * 32];
  __shared__ __align__(16) unsigned short sB[2][128 * 32];

  const int tid = threadIdx.x, lane = tid & 63, wid = tid >> 6;
  const int wr = (wid >> 1) * 64, wc = (wid & 1) * 64;

  const int rowBase = rowOff[g] + rb * 128;

  // ---- A staging (gload16) ----
  const int lr = lane >> 2, lc = lane & 3;
  const int ra0 = wid * 32 + lr, ra1 = wid * 32 + 16 + lr;
  const unsigned short* aG0 =
      Abuf + (size_t)(rowBase + ra0) * FD + ((lc ^ ((ra0 >> 1) & 3)) * 8);
  const unsigned short* aG1 =
      Abuf + (size_t)(rowBase + ra1) * FD + ((lc ^ ((ra1 >> 1) & 3)) * 8);

  // ---- B staging: thread = kg (rows 4kg..4kg+3) x cols n = nq+32j ----
  const int kg = tid >> 5, nq = tid & 31;
  const float* bp;
  if (g < NE)
    bp = w_down + (size_t)g * FD * HD + (size_t)(4 * kg) * HD + cb * 128 + nq;
  else
    bp = ws_down + (size_t)((g - NE) * FD + 4 * kg) * HD + cb * 128 + nq;
  const float* bp0 = bp;
  const float* bp1 = bp + HD;
  const float* bp2 = bp + 2 * HD;
  const float* bp3 = bp + 3 * HD;
  // word index for (n = nq+32j, kp0 = 2kg); kp1 word adjacent (+1)
  const int bw0 = nq * 16 + (((kg >> 1) ^ ((nq >> 2) & 3)) << 2) + ((2 * kg) & 3);
  // consecutive j: += 32*16 = 512 words

  const f32x4 fz = {0.f, 0.f, 0.f, 0.f};
  f32x4 acc[4][4];
#pragma unroll
  for (int m = 0; m < 4; ++m)
#pragma unroll
    for (int n = 0; n < 4; ++n) acc[m][n] = fz;

  float b0[4], b1[4], b2[4], b3[4];

  auto STAGEA = [&](int bu, int s) {
    size_t ko = (size_t)s * 32;
    gload16(aG0 + ko, &sA[bu][wid * 1024]);
    gload16(aG1 + ko, &sA[bu][wid * 1024 + 512]);
  };
  auto LOADB = [&](int s) {
    size_t o = (size_t)s * 32 * HD;
#pragma unroll
    for (int j = 0; j < 4; ++j) {
      b0[j] = bp0[o + 32 * j];
      b1[j] = bp1[o + 32 * j];
      b2[j] = bp2[o + 32 * j];
      b3[j] = bp3[o + 32 * j];
    }
  };
  auto STOREB = [&](int bu) {
    unsigned* bw_ = (unsigned*)sB[bu];
#pragma unroll
    for (int j = 0; j < 4; ++j) {
      u32x2 v;
      v.x = cvt_pk(b0[j], b1[j]);
      v.y = cvt_pk(b2[j], b3[j]);
      *(u32x2*)&bw_[bw0 + 512 * j] = v;
    }
  };

  auto COMPUTE = [&](int bu) {
    const int ksel = lane >> 4;
    short8 av[4], bv[4];
#pragma unroll
    for (int n = 0; n < 4; ++n) {
      int c = wc + n * 16 + (lane & 15);
      int idx = c * 32 + ((ksel ^ ((c >> 2) & 3)) << 3);
      bv[n] = *(const short8*)&sB[bu][idx];
    }
#pragma unroll
    for (int m = 0; m < 4; ++m) {
      int r = wr + m * 16 + (lane & 15);
      av[m] = *(const short8*)&sA[bu][r * 32 + ((ksel ^ ((r >> 1) & 3)) << 3)];
    }
#pragma unroll
    for (int m = 0; m < 4; ++m)
#pragma unroll
      for (int n = 0; n < 4; ++n) acc[m][n] = mfma16(av[m], bv[n], acc[m][n]);
  };

  const int NK = FD / 32;  // 44
  LOADB(0);
  STAGEA(0, 0);
  STOREB(0);
  LOADB(1);
  __syncthreads();
#pragma unroll 1
  for (int s = 0; s < NK; ++s) {
    int bu = s & 1;
    if (s + 1 < NK) STAGEA(bu ^ 1, s + 1);
    COMPUTE(bu);
    if (s + 1 < NK) STOREB(bu ^ 1);
    if (s + 2 < NK) LOADB(s + 2);
    __syncthreads();
  }

#pragma unroll
  for (int m = 0; m < 4; ++m)
#pragma unroll
    for (int r = 0; r < 4; ++r) {
      int rl = wr + m * 16 + ((lane >> 4) << 2) + r;
      int gi = rb * 128 + rl;
      if (gi < count) {
        int t = tok[g * TT + gi];
        float* op = out + (size_t)t * HD + cb * 128;
#pragma unroll
        for (int n = 0; n < 4; ++n)
          atomicAdd(op + wc + n * 16 + (lane & 15), acc[m][n][r]);
      }
    }
}

// ---------------------------------------------------------------------------
extern "C" void kernel_launch(void* const* d_in, const int* in_sizes, int n_in,
                              void* d_out, int out_size, void* d_ws, size_t ws_size,
                              hipStream_t stream) {
  const float* x      = (const float*)d_in[0];
  const float* gw     = (const float*)d_in[1];
  const float* w_gate = (const float*)d_in[2];
  const float* w_up   = (const float*)d_in[3];
  const float* w_down = (const float*)d_in[4];
  const float* wsg    = (const float*)d_in[5];
  const float* wsu    = (const float*)d_in[6];
  const float* wsd    = (const float*)d_in[7];
  float* out = (float*)d_out;

  char* ws = (char*)d_ws;
  float* dense_w = (float*)(ws);                       // 128KB
  int*   tok     = (int*)(ws + (140 << 10));
  float* scale   = (float*)(ws + (290 << 10));
  int*   counts  = (int*)(ws + (440 << 10));
  int*   rowOff  = (int*)(ws + (441 << 10));
  int*   work1   = (int*)(ws + (444 << 10));
  int*   work2   = (int*)(ws + (456 << 10));
  int*   meta    = (int*)(ws + (464 << 10));
  unsigned short* Abuf = (unsigned short*)(ws + (1ull  << 20));   // 34.6MB
  unsigned short* xb   = (unsigned short*)(ws + (36ull << 20));   // 8MB

  hipMemsetAsync(d_out, 0, (size_t)out_size * sizeof(float), stream);
  gate_kernel<<<TT / 4, 256, 0, stream>>>(x, gw, dense_w);
  build_lists<<<NG, 64, 0, stream>>>(dense_w, tok, scale, counts);
  prefix_kernel<<<1, 512, 0, stream>>>(counts, rowOff, work1, work2, meta);
  cvt_bf16_kernel<<<(TT * HD / 4 + 255) / 256, 256, 0, stream>>>(x, xb, TT * HD / 4);

  gemm1_v12<<<MAXW1, 256, 0, stream>>>(
      xb, w_gate, w_up, wsg, wsu, tok, scale, counts, rowOff, work1, meta, Abuf);
  gemm2_v12<<<MAXW2, 256, 0, stream>>>(
      Abuf, w_down, wsd, tok, counts, rowOff, work2, meta, out);
}